// Round 3
// baseline (8000.632 us; speedup 1.0000x reference)
//
#include <hip/hip_runtime.h>
#include <math.h>

// Problem constants (from reference)
#define HH   512      // hidden
#define BB   32       // batch
#define TENC 256      // encoder steps
#define TDEC 32       // decoder steps
#define VV   50000    // vocab
#define SOSTOK 2
#define G3H  1536     // 3*H
#define NCG  49       // ceil(50000/1024) logits col-groups
#define NB   256      // persistent scan grid (1 block per CU, forced by LDS)
#define NKQ  8        // k-split across the 8 waves of a 512-thread block

__device__ __forceinline__ float sigmoidf_(float x) { return 1.0f / (1.0f + expf(-x)); }

// ---------------------------------------------------------------------------
// Transpose W [1536][512] -> WT [512][1536] (scalar, 32x32 LDS tiles).
// ---------------------------------------------------------------------------
__global__ __launch_bounds__(256) void transpose_w(
    const float* __restrict__ in, float* __restrict__ out)
{
    __shared__ float tile[32][33];
    const int kt = blockIdx.x * 32;   // over HH
    const int jt = blockIdx.y * 32;   // over G3H
    const int tx = threadIdx.x & 31, ty = threadIdx.x >> 5;  // 32 x 8
#pragma unroll
    for (int l = 0; l < 4; l++) {
        int j = jt + ty + l * 8;
        tile[ty + l * 8][tx] = in[(size_t)j * HH + kt + tx];
    }
    __syncthreads();
#pragma unroll
    for (int l = 0; l < 4; l++) {
        int k = kt + ty + l * 8;
        out[(size_t)k * G3H + jt + tx] = tile[tx][ty + l * 8];
    }
}

// ---------------------------------------------------------------------------
// Transpose Whh [1536][512] viewed as [1536][128] float4 -> WT4 [128][1536]f4.
// WT4[k4][j] = Whh[j][4k4..4k4+3].
// ---------------------------------------------------------------------------
__global__ __launch_bounds__(256) void transpose_w4(
    const float4* __restrict__ in, float4* __restrict__ out)
{
    __shared__ float4 tile[16][17];
    const int kt = blockIdx.x * 16;   // over 128
    const int jt = blockIdx.y * 16;   // over 1536
    const int tx = threadIdx.x & 15, ty = threadIdx.x >> 4;  // 16 x 16
    tile[ty][tx] = in[(size_t)(jt + ty) * 128 + kt + tx];
    __syncthreads();
    out[(size_t)(kt + ty) * G3H + jt + tx] = tile[tx][ty];
}

// ---------------------------------------------------------------------------
// gx kernel (TN, coalesced). __launch_bounds__(256,3): VGPR cap ~170 >= ~95
// live -> no scratch spill (round-2 lesson), 3 blocks/CU.
// ---------------------------------------------------------------------------
__global__ __launch_bounds__(256, 3) void gxT_kernel(
    const int* __restrict__ idxs, const float* __restrict__ emb,
    const float* __restrict__ WT, const float* __restrict__ bias,
    float* __restrict__ out, int dec_mode)
{
    __shared__ __align__(16) float As[16][HH];
    const int tid = threadIdx.x;
    const int m0 = blockIdx.x * 16;

    for (int l = tid; l < 16 * HH; l += 256) {
        int r = l >> 9, k = l & (HH - 1);
        int m = m0 + r;
        int t = m >> 5, b = m & 31;
        int idx;
        if (dec_mode) idx = (t == 0) ? SOSTOK : idxs[b * TDEC + (t - 1)];
        else          idx = idxs[b * TENC + t];
        float v = emb[(size_t)idx * HH + k];
        if (dec_mode) v = fmaxf(v, 0.0f);
        As[r][k] = v;
    }
    __syncthreads();

    const int j0 = blockIdx.y * 1024 + tid * 4;
    if (j0 >= G3H) return;

    float acc[16][4];
#pragma unroll
    for (int r = 0; r < 16; r++)
#pragma unroll
        for (int jj = 0; jj < 4; jj++) acc[r][jj] = 0.0f;

    for (int kc = 0; kc < HH; kc += 4) {
        float4 w0 = *(const float4*)(WT + (size_t)(kc + 0) * G3H + j0);
        float4 w1 = *(const float4*)(WT + (size_t)(kc + 1) * G3H + j0);
        float4 w2 = *(const float4*)(WT + (size_t)(kc + 2) * G3H + j0);
        float4 w3 = *(const float4*)(WT + (size_t)(kc + 3) * G3H + j0);
#pragma unroll
        for (int r = 0; r < 16; r++) {
            float4 a = *(const float4*)(&As[r][kc]);
            acc[r][0] += a.x * w0.x + a.y * w1.x + a.z * w2.x + a.w * w3.x;
            acc[r][1] += a.x * w0.y + a.y * w1.y + a.z * w2.y + a.w * w3.y;
            acc[r][2] += a.x * w0.z + a.y * w1.z + a.z * w2.z + a.w * w3.z;
            acc[r][3] += a.x * w0.w + a.y * w1.w + a.z * w2.w + a.w * w3.w;
        }
    }

    float4 bv = *(const float4*)(bias + j0);
#pragma unroll
    for (int r = 0; r < 16; r++) {
        float4 o;
        o.x = acc[r][0] + bv.x;
        o.y = acc[r][1] + bv.y;
        o.z = acc[r][2] + bv.z;
        o.w = acc[r][3] + bv.w;
        *(float4*)(out + (size_t)(m0 + r) * G3H + j0) = o;
    }
}

// ---------------------------------------------------------------------------
// Persistent GRU scan: ONE launch for all T steps; grid-wide sync between
// steps via device-scope atomic barrier (all 256 blocks co-resident: 112 KB
// LDS -> exactly 1 block/CU, grid == CU count).
// Block bid: bq = bid&7 (4 batch rows), it = bid>>3 (16 hidden outputs).
// Weight slice (3 gates x 16 i x 512 k fp32 = 96 KB) loaded into LDS ONCE.
// Wave = k-octant (64 k each), lanes = (b, il): weight reads are 16
// consecutive float4 (256 B) broadcast to 4 lanes -> conflict-free.
// Cross-wave k-reduction through LDS; 64 output lanes do gate math.
// ---------------------------------------------------------------------------
__global__ __launch_bounds__(512, 1) void gru_scan(
    const float4* __restrict__ WT4,   // [128][1536] float4
    const float* __restrict__ bhh,    // [3H]
    const float* __restrict__ gx_all, // [T][B][3H]
    float* __restrict__ hbufA,        // mode0: ping (holds h0; ends with h_T)
    float* __restrict__ hbufB,        // mode0: pong
    float* __restrict__ h_all,        // mode1: [T][B][H] outputs
    int T, int mode,
    unsigned* __restrict__ barcnt)    // zero-initialized
{
    __shared__ __align__(16) float4 Wlds[3 * 128 * 16];  // [g][k4][il]  98304 B
    __shared__ __align__(16) float4 hs[4 * 129];         // padded: bank-spread  8256 B
    __shared__ float part[3][NKQ][64];                   // 6144 B

    const int tid = threadIdx.x;
    const int bid = blockIdx.x;
    const int bq = bid & 7;
    const int it = bid >> 3;
    const int kq = tid >> 6;          // wave index = k-octant
    const int lane = tid & 63;
    const int bl = lane >> 4;         // b within quad
    const int il = lane & 15;

    // one-time weight slice load: Wlds[((g*128+k4)*16)+il]
    for (int idx = tid; idx < 3 * 128 * 16; idx += 512) {
        int g = idx >> 11, k4 = (idx >> 4) & 127, jl = idx & 15;
        Wlds[idx] = WT4[(size_t)k4 * G3H + g * HH + it * 16 + jl];
    }

    const int ob = bq * 4 + (tid >> 4);     // output row   (valid for tid<64)
    const int oi = it * 16 + (tid & 15);    // output col   (valid for tid<64)
    float bhr = 0.f, bhz = 0.f, bhn = 0.f;
    if (tid < 64) { bhr = bhh[oi]; bhz = bhh[HH + oi]; bhn = bhh[2 * HH + oi]; }

    for (int t = 0; t < T; ++t) {
        const float* h_in;
        float* h_out;
        if (mode == 0) {
            h_in  = (t & 1) ? hbufB : hbufA;
            h_out = (t & 1) ? hbufA : hbufB;
        } else {
            h_in  = (t == 0) ? hbufA : h_all + (size_t)(t - 1) * BB * HH;
            h_out = h_all + (size_t)t * BB * HH;
        }
        const float* gx_t = gx_all + (size_t)t * BB * G3H;

        // stage this block's 4 h rows (padded layout: b stride 129 float4)
        {
            int b = tid >> 7, rem = tid & 127;
            hs[b * 129 + rem] = ((const float4*)h_in)[bq * 512 + tid];
        }
        // early gx prefetch for output lanes (consumed after reduction)
        float gxr = 0.f, gxz = 0.f, gxn = 0.f;
        if (tid < 64) {
            gxr = gx_t[ob * G3H + oi];
            gxz = gx_t[ob * G3H + HH + oi];
            gxn = gx_t[ob * G3H + 2 * HH + oi];
        }
        __syncthreads();

        // partial dots over this wave's 64-k slice
        float ar = 0.f, az = 0.f, an = 0.f;
        const float4* hp4 = &hs[bl * 129 + kq * 16];
        const float4* w0  = &Wlds[(0 * 128 + kq * 16) * 16 + il];
        const float4* w1  = &Wlds[(1 * 128 + kq * 16) * 16 + il];
        const float4* w2  = &Wlds[(2 * 128 + kq * 16) * 16 + il];
#pragma unroll
        for (int m = 0; m < 16; ++m) {
            float4 h4 = hp4[m];
            float4 a4 = w0[m * 16];
            float4 b4 = w1[m * 16];
            float4 c4 = w2[m * 16];
            ar += h4.x * a4.x + h4.y * a4.y + h4.z * a4.z + h4.w * a4.w;
            az += h4.x * b4.x + h4.y * b4.y + h4.z * b4.z + h4.w * b4.w;
            an += h4.x * c4.x + h4.y * c4.y + h4.z * c4.z + h4.w * c4.w;
        }
        part[0][kq][lane] = ar;
        part[1][kq][lane] = az;
        part[2][kq][lane] = an;
        __syncthreads();

        if (tid < 64) {
            float sr = 0.f, sz = 0.f, sn = 0.f;
#pragma unroll
            for (int q = 0; q < NKQ; ++q) {
                sr += part[0][q][tid];
                sz += part[1][q][tid];
                sn += part[2][q][tid];
            }
            float r = sigmoidf_(gxr + sr + bhr);
            float z = sigmoidf_(gxz + sz + bhz);
            float n = tanhf(gxn + r * (sn + bhn));
            float hprev = ((const float*)hs)[(tid >> 4) * 516 + oi];
            h_out[(size_t)ob * HH + oi] = (1.0f - z) * n + z * hprev;
        }

        // grid-wide barrier (skip after final step; kernel end flushes)
        if (t + 1 < T) {
            __syncthreads();
            if (tid == 0) {
                __threadfence();   // release h_out to device scope
                __hip_atomic_fetch_add(barcnt, 1u, __ATOMIC_RELEASE,
                                       __HIP_MEMORY_SCOPE_AGENT);
                unsigned target = (unsigned)NB * (unsigned)(t + 1);
                while (__hip_atomic_load(barcnt, __ATOMIC_ACQUIRE,
                                         __HIP_MEMORY_SCOPE_AGENT) < target) {
                    __builtin_amdgcn_s_sleep(2);
                }
                __threadfence();   // acquire: invalidate stale caches
            }
            __syncthreads();
        }
    }
}

// ---------------------------------------------------------------------------
// Fused logits GEMM + partial logsumexp + target gather.
// __launch_bounds__(256,3): VGPR cap ~170 -> no scratch spill (round-2: 393MB
// of spill WRITE_SIZE at default budget), 3 blocks/CU.
// ---------------------------------------------------------------------------
__global__ __launch_bounds__(256, 3) void logits_kernel(
    const float* __restrict__ Hall,   // [1024][512]
    const float* __restrict__ Wg,     // [512][50000]
    const float* __restrict__ bg,     // [50000]
    const int* __restrict__ qw,       // [32][32] targets
    float* __restrict__ pmax,         // [49][1024]
    float* __restrict__ psum,         // [49][1024]
    float* __restrict__ tgt_logit)    // [1024]
{
    __shared__ __align__(16) float As[16][HH];
    __shared__ float wred[16][4];
    const int tid = threadIdx.x;
    const int m0 = blockIdx.x * 16;
    const int lane = tid & 63, wid = tid >> 6;

    for (int l = tid; l < 16 * HH; l += 256) {
        int r = l >> 9, k = l & (HH - 1);
        As[r][k] = Hall[(size_t)(m0 + r) * HH + k];
    }
    __syncthreads();

    const int j0 = blockIdx.y * 1024 + tid * 4;
    const bool valid = (j0 < VV);

    float acc[16][4];
#pragma unroll
    for (int r = 0; r < 16; r++)
#pragma unroll
        for (int jj = 0; jj < 4; jj++) acc[r][jj] = 0.0f;

    if (valid) {
        for (int kc = 0; kc < HH; kc += 4) {
            float4 w0 = *(const float4*)(Wg + (size_t)(kc + 0) * VV + j0);
            float4 w1 = *(const float4*)(Wg + (size_t)(kc + 1) * VV + j0);
            float4 w2 = *(const float4*)(Wg + (size_t)(kc + 2) * VV + j0);
            float4 w3 = *(const float4*)(Wg + (size_t)(kc + 3) * VV + j0);
#pragma unroll
            for (int r = 0; r < 16; r++) {
                float4 a = *(const float4*)(&As[r][kc]);
                acc[r][0] += a.x * w0.x + a.y * w1.x + a.z * w2.x + a.w * w3.x;
                acc[r][1] += a.x * w0.y + a.y * w1.y + a.z * w2.y + a.w * w3.y;
                acc[r][2] += a.x * w0.z + a.y * w1.z + a.z * w2.z + a.w * w3.z;
                acc[r][3] += a.x * w0.w + a.y * w1.w + a.z * w2.w + a.w * w3.w;
            }
        }
        float4 bv = *(const float4*)(bg + j0);
#pragma unroll
        for (int r = 0; r < 16; r++) {
            acc[r][0] += bv.x; acc[r][1] += bv.y; acc[r][2] += bv.z; acc[r][3] += bv.w;
        }
#pragma unroll
        for (int r = 0; r < 16; r++) {
            int m = m0 + r, t = m >> 5, b = m & 31;
            int tj = qw[b * TDEC + t];
            if (tj >= j0 && tj < j0 + 4) tgt_logit[m] = acc[r][tj - j0];
        }
    }

    float rowmax[16];
#pragma unroll
    for (int r = 0; r < 16; r++) {
        float v = valid ? fmaxf(fmaxf(acc[r][0], acc[r][1]), fmaxf(acc[r][2], acc[r][3]))
                        : -INFINITY;
        for (int off = 32; off > 0; off >>= 1) v = fmaxf(v, __shfl_xor(v, off));
        if (lane == 0) wred[r][wid] = v;
    }
    __syncthreads();
#pragma unroll
    for (int r = 0; r < 16; r++)
        rowmax[r] = fmaxf(fmaxf(wred[r][0], wred[r][1]), fmaxf(wred[r][2], wred[r][3]));
    __syncthreads();

#pragma unroll
    for (int r = 0; r < 16; r++) {
        float s = 0.0f;
        if (valid) {
            s = expf(acc[r][0] - rowmax[r]) + expf(acc[r][1] - rowmax[r])
              + expf(acc[r][2] - rowmax[r]) + expf(acc[r][3] - rowmax[r]);
        }
        for (int off = 32; off > 0; off >>= 1) s += __shfl_xor(s, off);
        if (lane == 0) wred[r][wid] = s;
    }
    __syncthreads();

    if (tid < 16) {
        int r = tid;
        float S = wred[r][0] + wred[r][1] + wred[r][2] + wred[r][3];
        pmax[blockIdx.y * 1024 + m0 + r] = rowmax[r];
        psum[blockIdx.y * 1024 + m0 + r] = S;
    }
}

// ---------------------------------------------------------------------------
__global__ __launch_bounds__(256) void loss_kernel(
    const float* __restrict__ pmax, const float* __restrict__ psum,
    const float* __restrict__ tgt_logit, float* __restrict__ out)
{
    const int tid = threadIdx.x;
    float local = 0.0f;
    for (int m = tid; m < 1024; m += 256) {
        float M = -INFINITY;
        for (int cg = 0; cg < NCG; cg++) M = fmaxf(M, pmax[cg * 1024 + m]);
        float S = 0.0f;
        for (int cg = 0; cg < NCG; cg++) S += psum[cg * 1024 + m] * expf(pmax[cg * 1024 + m] - M);
        local += M + logf(S) - tgt_logit[m];
    }
    __shared__ float red[256];
    red[tid] = local;
    __syncthreads();
    for (int s = 128; s > 0; s >>= 1) {
        if (tid < s) red[tid] += red[tid + s];
        __syncthreads();
    }
    if (tid == 0) out[0] = red[0] / (float)TDEC;
}

// ---------------------------------------------------------------------------
extern "C" void kernel_launch(void* const* d_in, const int* in_sizes, int n_in,
                              void* d_out, int out_size, void* d_ws, size_t ws_size,
                              hipStream_t stream)
{
    const int*   cw     = (const int*)  d_in[0];
    const int*   qw     = (const int*)  d_in[1];
    const float* emb_e  = (const float*)d_in[2];
    const float* emb_d  = (const float*)d_in[3];
    const float* Wih_e  = (const float*)d_in[4];
    const float* Whh_e  = (const float*)d_in[5];
    const float* bih_e  = (const float*)d_in[6];
    const float* bhh_e  = (const float*)d_in[7];
    const float* Wih_d  = (const float*)d_in[8];
    const float* Whh_d  = (const float*)d_in[9];
    const float* bih_d  = (const float*)d_in[10];
    const float* bhh_d  = (const float*)d_in[11];
    const float* Wg     = (const float*)d_in[12];
    const float* bg     = (const float*)d_in[13];

    // Workspace layout (floats); ~72 MB
    float* ws      = (float*)d_ws;
    float* gx_enc  = ws;                                   // 8192*1536
    float* gx_dec  = gx_enc + (size_t)8192 * G3H;          // 1024*1536
    float* hbuf0   = gx_dec + (size_t)1024 * G3H;          // 32*512
    float* hbuf1   = hbuf0 + BB * HH;                      // 32*512
    float* h_all   = hbuf1 + BB * HH;                      // 1024*512
    float* pmax    = h_all + (size_t)1024 * HH;            // 49*1024
    float* psum    = pmax + NCG * 1024;                    // 49*1024
    float* tgt_l   = psum + NCG * 1024;                    // 1024
    float* WihT_e  = tgt_l + 1024;                         // 512*1536
    float* WihT_d  = WihT_e + (size_t)HH * G3H;            // 512*1536
    float* WhhT4_e = WihT_d + (size_t)HH * G3H;            // 512*1536 (as f4)
    float* WhhT4_d = WhhT4_e + (size_t)HH * G3H;           // 512*1536 (as f4)
    unsigned* barc = (unsigned*)(WhhT4_d + (size_t)HH * G3H);  // 2 counters

    // zero h0 and barrier counters (ws is re-poisoned before every launch)
    hipMemsetAsync(hbuf0, 0, BB * HH * sizeof(float), stream);
    hipMemsetAsync(barc, 0, 2 * sizeof(unsigned), stream);

    // Phase 0: weight transposes
    transpose_w <<<dim3(16, 48), 256, 0, stream>>>(Wih_e, WihT_e);
    transpose_w <<<dim3(16, 48), 256, 0, stream>>>(Wih_d, WihT_d);
    transpose_w4<<<dim3(8, 96),  256, 0, stream>>>((const float4*)Whh_e, (float4*)WhhT4_e);
    transpose_w4<<<dim3(8, 96),  256, 0, stream>>>((const float4*)Whh_d, (float4*)WhhT4_d);

    // Phase 1: encoder gx (parallel over all timesteps)
    gxT_kernel<<<dim3(512, 2), 256, 0, stream>>>(cw, emb_e, WihT_e, bih_e, gx_enc, 0);

    // Phase 2: encoder scan — ONE persistent launch, 256 internal steps.
    // T even -> final h lands back in hbuf0.
    gru_scan<<<NB, 512, 0, stream>>>((const float4*)WhhT4_e, bhh_e, gx_enc,
                                     hbuf0, hbuf1, (float*)nullptr, TENC, 0, barc + 0);

    // Phase 3: decoder gx
    gxT_kernel<<<dim3(64, 2), 256, 0, stream>>>(qw, emb_d, WihT_d, bih_d, gx_dec, 1);

    // Phase 4: decoder scan — ONE persistent launch, chains through h_all.
    gru_scan<<<NB, 512, 0, stream>>>((const float4*)WhhT4_d, bhh_d, gx_dec,
                                     hbuf0, (float*)nullptr, h_all, TDEC, 1, barc + 1);

    // Phase 5: batched logits + online logsumexp partials
    logits_kernel<<<dim3(64, NCG), 256, 0, stream>>>(h_all, Wg, bg, qw, pmax, psum, tgt_l);

    // Phase 6: combine -> scalar loss
    loss_kernel<<<1, 256, 0, stream>>>(pmax, psum, tgt_l, (float*)d_out);
}